// Round 11
// baseline (1730.091 us; speedup 1.0000x reference)
//
#include <hip/hip_runtime.h>
#include <cmath>

// (B, L, D, H) = (256, 32, 512, 512)
#define B_   256
#define L_   32
#define H_   512
#define NH5  2560   // 5*H
#define N2   5120   // 2*NH5 : [al | ar] output width
#define SCALE 0.044194173824159216f  // 1/sqrt(H)

// ---------------- persistent device state (re-initialized every launch) ----
__device__ float g_h [B_*L_*H_];          // [b][slot][j] node hidden
__device__ float g_c [B_*L_*H_];          // [b][slot][j] node cell
__device__ float g_al[(size_t)B_*L_*NH5]; // [b][slot][k] Wl @ h_slot
__device__ float g_ar[(size_t)B_*L_*NH5]; // [b][slot][k] Wr @ h_slot
__device__ float g_logit[B_*L_];          // pair logit keyed by LEFT slot
__device__ int   g_list[B_*L_];           // active slot list (sequence order)
__device__ int   g_count[B_];             // active node count
__device__ int   g_merged[B_];            // slot merged last iter (-1 done, -2 init)
__device__ int   g_mpos[B_];              // list position of last merge
__device__ int   g_rows[B_*L_];           // ordered compact list of active rows
__device__ int   g_nrows;
__device__ int   g_mlist[2][B_];          // batches merged this iter (parity)
__device__ int   g_cnt[2];

__device__ __forceinline__ float sigm(float x) { return 1.0f / (1.0f + expf(-x)); }

// vectorized gate loaders: d[u] = a[off+u] + b[off+u] + bc[off+u]
__device__ __forceinline__ void gate4(float* d, const float* __restrict__ a,
                                      const float* __restrict__ b,
                                      const float* __restrict__ bc, int off) {
  float4 x = *(const float4*)(a + off);
  float4 y = *(const float4*)(b + off);
  float4 z = *(const float4*)(bc + off);
  d[0]=x.x+y.x+z.x; d[1]=x.y+y.y+z.y; d[2]=x.z+y.z+z.z; d[3]=x.w+y.w+z.w;
}
__device__ __forceinline__ void gate2(float* d, const float* __restrict__ a,
                                      const float* __restrict__ b,
                                      const float* __restrict__ bc, int off) {
  float2 x = *(const float2*)(a + off);
  float2 y = *(const float2*)(b + off);
  float2 z = *(const float2*)(bc + off);
  d[0]=x.x+y.x+z.x; d[1]=x.y+y.y+z.y;
}

// ------ init: prefix-scan lengths, ordered row list, slot lists (fused) ----
__global__ __launch_bounds__(256) void scan_init(const int* __restrict__ length) {
  __shared__ int sw[4];
  __shared__ int s_off[256];
  __shared__ int s_len[256];
  const int t = threadIdx.x;
  const int len = length[t];
  s_len[t] = len;
  int v = len;
#pragma unroll
  for (int off = 1; off < 64; off <<= 1) {
    int o = __shfl_up(v, off, 64);
    if ((t & 63) >= off) v += o;
  }
  if ((t & 63) == 63) sw[t >> 6] = v;
  __syncthreads();
  int base = 0;
  for (int w = 0; w < (t >> 6); w++) base += sw[w];
  const int incl = base + v;
  s_off[t] = incl - len;
  if (t == 255) g_nrows = incl;
  g_count[t] = len; g_merged[t] = -2; g_mpos[t] = 0;
  if (t == 0) { g_cnt[0] = 0; g_cnt[1] = 0; }
  __syncthreads();
  for (int idx = t; idx < B_*L_; idx += 256) {      // fused fill_rows
    const int b = idx >> 5, s = idx & 31;
    g_list[idx] = s;
    if (s < s_len[b]) g_rows[s_off[b] + s] = idx;   // sorted by (b,slot)
  }
}

// ----- big row-compacted GEMMs: 256 thr, 256m x 128n, 16x8/thread, DBUF ----
// r9 tile (measured 301-308us) + double-buffered LDS: one barrier per K-step
// instead of two. r3's dbuf failure was VGPR-driven (56->124 collapsed occ
// 30->17.6%); the r9 tile is ALREADY at 124 VGPR and block-count-limited, so
// halving the barrier count is now a clean one-variable test. LDS 12->24.5KB
// (6 blocks/CU by LDS, not limiting). Fragments: stride-64 grouping, ~zero
// conflicts (1.4M measured). Per-output k-order unchanged -> bit-identical.
// MODE 0: word GEMM  A=x rows   -> g_h|g_c (+b_word)   N=1024, 8 n-tiles
// MODE 1: leaf GEMM  A=g_h rows -> g_al|g_ar           N=5120, 40 n-tiles
template<int MODE>
__global__ __launch_bounds__(256) void gemm_big(
    const float* __restrict__ Aext,
    const float* __restrict__ Bm,
    const float* __restrict__ bias)
{
  const int NR = g_nrows;
  const int bid = blockIdx.x;
  const int xcd = bid & 7, jj = bid >> 3;
  const int ntp = (MODE == 0) ? 1 : 5;       // n-tiles per XCD
  const int mt = jj / ntp;
  const int nt = xcd * ntp + (jj - mt * ntp);
  const int m0 = mt * 256;
  if (m0 >= NR) return;                      // uniform early exit
  const int n0 = nt * 128;

  const int tid = threadIdx.x;
  const int w = tid >> 6, l = tid & 63;
  const int tx = (w & 1) * 8 + (l & 7);      // 0..15; cols tx*4 + 64q, q=0..1
  const int ty = (w >> 1) * 8 + (l >> 3);    // 0..15; rows ty*4 + 64p, p=0..3

  __shared__ float As[2][8][256];
  __shared__ float Bs[2][8][128];

  // A staging: 256 rows x 8 k; thread owns row tid (2 float4)
  int mr = m0 + tid; if (mr >= NR) mr = NR - 1;
  const float* Abase = (MODE == 0) ? Aext : g_h;
  const float* aptr = Abase + (size_t)g_rows[mr] * 512;

  // B staging: 128 rows x 8 k; thread = (row tid>>1, k-half (tid&1)*4)
  const int rb = tid >> 1, qb = (tid & 1) * 4;
  const float* bptr;
  {
    int nrow = n0 + rb;
    if (MODE == 0) bptr = Bm + (size_t)nrow * 512 + qb;
    else bptr = Bm + (nrow < NH5 ? (size_t)nrow * 1024
                                 : (size_t)(nrow - NH5) * 1024 + 512) + qb;
  }

  // prologue: stage K-step 0 into buffer 0
  float4 a0 = *(const float4*)(aptr), a1 = *(const float4*)(aptr + 4);
  float4 bv = *(const float4*)(bptr);
  As[0][0][tid]=a0.x; As[0][1][tid]=a0.y; As[0][2][tid]=a0.z; As[0][3][tid]=a0.w;
  As[0][4][tid]=a1.x; As[0][5][tid]=a1.y; As[0][6][tid]=a1.z; As[0][7][tid]=a1.w;
  Bs[0][qb+0][rb]=bv.x; Bs[0][qb+1][rb]=bv.y; Bs[0][qb+2][rb]=bv.z; Bs[0][qb+3][rb]=bv.w;
  __syncthreads();

  float acc[16][8] = {};

  for (int s = 0; s < 64; ++s) {
    const int cur = s & 1;
    if (s < 63) {                            // prefetch next K-step to regs
      const int ko = 8 * (s + 1);
      a0 = *(const float4*)(aptr + ko);
      a1 = *(const float4*)(aptr + ko + 4);
      bv = *(const float4*)(bptr + ko);
    }
#pragma unroll
    for (int k = 0; k < 8; k++) {
      float af[16], bf[8];
#pragma unroll
      for (int p = 0; p < 4; p++) {
        float4 t = *(const float4*)&As[cur][k][ty*4 + 64*p];
        af[p*4+0]=t.x; af[p*4+1]=t.y; af[p*4+2]=t.z; af[p*4+3]=t.w;
      }
#pragma unroll
      for (int q = 0; q < 2; q++) {
        float4 t = *(const float4*)&Bs[cur][k][tx*4 + 64*q];
        bf[q*4+0]=t.x; bf[q*4+1]=t.y; bf[q*4+2]=t.z; bf[q*4+3]=t.w;
      }
#pragma unroll
      for (int i = 0; i < 16; i++)
#pragma unroll
        for (int j = 0; j < 8; j++)
          acc[i][j] = fmaf(af[i], bf[j], acc[i][j]);
    }
    if (s < 63) {                            // stage into the idle buffer
      const int nx = cur ^ 1;
      As[nx][0][tid]=a0.x; As[nx][1][tid]=a0.y; As[nx][2][tid]=a0.z; As[nx][3][tid]=a0.w;
      As[nx][4][tid]=a1.x; As[nx][5][tid]=a1.y; As[nx][6][tid]=a1.z; As[nx][7][tid]=a1.w;
      Bs[nx][qb+0][rb]=bv.x; Bs[nx][qb+1][rb]=bv.y; Bs[nx][qb+2][rb]=bv.z; Bs[nx][qb+3][rb]=bv.w;
      __syncthreads();                       // one barrier per K-step
    }
  }

#pragma unroll
  for (int p = 0; p < 4; p++)
#pragma unroll
  for (int i = 0; i < 4; i++) {
    int mrow = m0 + 64*p + ty*4 + i;
    if (mrow >= NR) continue;
    int crow = g_rows[mrow];
#pragma unroll
    for (int q = 0; q < 2; q++) {
      int n = n0 + 64*q + tx*4;              // 4-aligned; never straddles 512/NH5
      float4 v = make_float4(acc[p*4+i][q*4+0], acc[p*4+i][q*4+1],
                             acc[p*4+i][q*4+2], acc[p*4+i][q*4+3]);
      if (MODE == 0) {
        float4 b4 = *(const float4*)(bias + n);
        v.x += b4.x; v.y += b4.y; v.z += b4.z; v.w += b4.w;
        if (n < H_) *(float4*)(g_h + (size_t)crow*H_ + n)        = v;
        else        *(float4*)(g_c + (size_t)crow*H_ + (n - H_)) = v;
      } else {
        if (n < NH5) *(float4*)(g_al + (size_t)crow*NH5 + n)         = v;
        else         *(float4*)(g_ar + (size_t)crow*NH5 + (n - NH5)) = v;
      }
    }
  }
}

// ---------------- iteration-0 logits (float2 vectorized) -------------------
__global__ __launch_bounds__(256) void iter0_logits(const int* __restrict__ length,
                                                    const float* __restrict__ bc,
                                                    const float* __restrict__ qv) {
  __shared__ float sred[4];
  const int p = blockIdx.x, b = blockIdx.y;
  if (p >= length[b] - 1) return;            // inactive pair: never read
  const float* al = g_al + (size_t)(b*L_ + p)*NH5;
  const float* ar = g_ar + (size_t)(b*L_ + p + 1)*NH5;
  const float* cl = g_c  + (size_t)(b*L_ + p)*H_;
  const float* cr = g_c  + (size_t)(b*L_ + p + 1)*H_;
  const int j0 = threadIdx.x * 2;
  float vi[2], vfl[2], vfr[2], vu[2], vo[2];
  gate2(vi , al, ar, bc,        j0);
  gate2(vfl, al, ar, bc, H_   + j0);
  gate2(vfr, al, ar, bc, 2*H_ + j0);
  gate2(vu , al, ar, bc, 3*H_ + j0);
  gate2(vo , al, ar, bc, 4*H_ + j0);
  float2 CL = *(const float2*)(cl + j0);
  float2 CR = *(const float2*)(cr + j0);
  float2 Q  = *(const float2*)(qv + j0);
  const float clv[2] = {CL.x, CL.y};
  const float crv[2] = {CR.x, CR.y};
  const float qq [2] = {Q.x, Q.y};
  float part = 0.f;
#pragma unroll
  for (int u = 0; u < 2; ++u) {
    float c = clv[u]*sigm(vfl[u]+1.f) + crv[u]*sigm(vfr[u]+1.f) + tanhf(vu[u])*sigm(vi[u]);
    float h = sigm(vo[u])*tanhf(c);
    part = fmaf(qq[u], h, part);
  }
#pragma unroll
  for (int off = 32; off; off >>= 1) part += __shfl_down(part, off, 64);
  if ((threadIdx.x & 63) == 0) sred[threadIdx.x >> 6] = part;
  __syncthreads();
  if (threadIdx.x == 0)
    g_logit[b*L_ + p] = (sred[0]+sred[1]+sred[2]+sred[3]) * SCALE;
}

// ---------------- per-iteration select + merge (+ final out write) ---------
// 512 threads (measured best): refresh keeps the EXACT 2x128-thread mapping
// (identical reduction order -> identical logits -> no argmax-flip risk);
// compose and output copy use all 512 threads, 1 element each.
// NEW: parallel list shift (was a serial tid==0 loop of up to 30 dependent
// global RMWs with 511 lanes idle). Pure int copy -> no numeric change.
__global__ __launch_bounds__(512) void select_merge(int iter,
    const int* __restrict__ length,
    const float* __restrict__ bc,
    const float* __restrict__ qv,
    float* __restrict__ out)
{
  __shared__ float sred[4];
  __shared__ int s_sel[3];
  const int b = blockIdx.x, tid = threadIdx.x;
  const bool fin = (iter == L_-2);
  if (b == 0 && tid == 0) g_cnt[(iter & 1) ^ 1] = 0;  // reset next iter's counter

  const int m     = g_count[b];
  const int pslot = g_merged[b];
  const int ppos  = g_mpos[b];
  int* list = g_list + b*L_;

  // ---- refresh the <=2 dirty pairs; threads 0..255 only, float4 over j ----
  if (iter > 0 && pslot >= 0) {
    const int half = tid >> 7, lt = tid & 127;
    int sl = -1, sr = -1;
    if (half == 0)      { if (ppos > 0)     { sl = list[ppos-1]; sr = list[ppos];   } }
    else if (half == 1) { if (ppos < m - 1) { sl = list[ppos];   sr = list[ppos+1]; } }
    float part = 0.f;
    if (sl >= 0) {
      const float* al = g_al + (size_t)(b*L_+sl)*NH5;
      const float* ar = g_ar + (size_t)(b*L_+sr)*NH5;
      const float* cl = g_c  + (size_t)(b*L_+sl)*H_;
      const float* cr = g_c  + (size_t)(b*L_+sr)*H_;
      const int j0 = lt * 4;
      float vi[4], vfl[4], vfr[4], vu[4], vo[4];
      gate4(vi , al, ar, bc,        j0);
      gate4(vfl, al, ar, bc, H_   + j0);
      gate4(vfr, al, ar, bc, 2*H_ + j0);
      gate4(vu , al, ar, bc, 3*H_ + j0);
      gate4(vo , al, ar, bc, 4*H_ + j0);
      float4 CL = *(const float4*)(cl + j0);
      float4 CR = *(const float4*)(cr + j0);
      float4 Q  = *(const float4*)(qv + j0);
      const float clv[4] = {CL.x,CL.y,CL.z,CL.w};
      const float crv[4] = {CR.x,CR.y,CR.z,CR.w};
      const float qq [4] = {Q.x,Q.y,Q.z,Q.w};
#pragma unroll
      for (int u = 0; u < 4; ++u) {
        float c = clv[u]*sigm(vfl[u]+1.f) + crv[u]*sigm(vfr[u]+1.f) + tanhf(vu[u])*sigm(vi[u]);
        float h = sigm(vo[u])*tanhf(c);
        part = fmaf(qq[u], h, part);
      }
    }
#pragma unroll
    for (int off = 32; off; off >>= 1) part += __shfl_down(part, off, 64);
    if ((tid & 63) == 0 && tid < 256) sred[tid >> 6] = part;
    __syncthreads();
    if (tid == 0   && ppos > 0)     g_logit[b*L_ + list[ppos-1]] = (sred[0]+sred[1])*SCALE;
    if (tid == 128 && ppos < m - 1) g_logit[b*L_ + list[ppos]]   = (sred[2]+sred[3])*SCALE;
  }

  const bool active = iter < (length[b] - 1);
  if (!active) {
    if (tid == 0) g_merged[b] = -1;
    if (fin)                                 // finished earlier: copy root
      out[(size_t)b*H_ + tid] = g_h[(size_t)(b*L_)*H_ + tid];
    return;
  }

  __syncthreads();   // refreshed g_logit visible block-wide

  // ---- wave-parallel argmax, first-max tie-break (lowest index) ----
  if (tid < 64) {
    float lg = -1e30f; int idx = tid;
    if (tid < m - 1) lg = g_logit[b*L_ + list[tid]];
#pragma unroll
    for (int off = 32; off; off >>= 1) {
      float olg = __shfl_down(lg, off, 64);
      int   oid = __shfl_down(idx, off, 64);
      if (olg > lg || (olg == lg && oid < idx)) { lg = olg; idx = oid; }
    }
    if (tid == 0) { s_sel[0] = idx; s_sel[1] = list[idx]; s_sel[2] = list[idx+1]; }
  }
  __syncthreads();
  const int pos = s_sel[0], sl = s_sel[1], sr = s_sel[2];

  // ---- merge compose (store h,c; 1 element/thread, 512 threads) ----
  {
    const float* al = g_al + (size_t)(b*L_+sl)*NH5;
    const float* ar = g_ar + (size_t)(b*L_+sr)*NH5;
    float*       cl = g_c  + (size_t)(b*L_+sl)*H_;
    const float* cr = g_c  + (size_t)(b*L_+sr)*H_;
    float*       hl = g_h  + (size_t)(b*L_+sl)*H_;
    const int j = tid;                       // H_ == 512 == blockDim
    float vi  = al[j]       + ar[j]       + bc[j];
    float vfl = al[H_+j]    + ar[H_+j]    + bc[H_+j];
    float vfr = al[2*H_+j]  + ar[2*H_+j]  + bc[2*H_+j];
    float vu  = al[3*H_+j]  + ar[3*H_+j]  + bc[3*H_+j];
    float vo  = al[4*H_+j]  + ar[4*H_+j]  + bc[4*H_+j];
    float c = cl[j]*sigm(vfl+1.f) + cr[j]*sigm(vfr+1.f) + tanhf(vu)*sigm(vi);
    float h = sigm(vo)*tanhf(c);
    cl[j] = c; hl[j] = h;                    // same-thread j: no RAW hazard
    if (fin)                                 // final merge: sl==0==root
      out[(size_t)b*H_ + j] = h;
  }

  // ---- parallel list shift: read-all -> barrier -> write-all ----
  {
    const bool doshift = (tid >= pos + 1) && (tid <= m - 2);
    int lv = 0;
    if (doshift) lv = list[tid + 1];
    __syncthreads();
    if (doshift) list[tid] = lv;
  }
  if (tid == 0) {
    g_count[b]  = m - 1;
    g_merged[b] = sl;
    g_mpos[b]   = pos;
    int k = atomicAdd(&g_cnt[iter & 1], 1);
    g_mlist[iter & 1][k] = b;
  }
}

// ------ per-iteration a_l/a_r GEMM: 32x64 tile, 4x4/thread, 128 threads ----
// EXACT r10 body (measured best loop: 1540 total). Grid 640, XCD swizzle.
__global__ __launch_bounds__(128) void gemm_iter(int par, const float* __restrict__ Wc)
{
  const int nact = g_cnt[par];
  const int bid = blockIdx.x;                // 640 blocks = 8 xcd x 10 nt x 8 mt
  const int xcd = bid & 7, jj = bid >> 3;    // jj 0..79
  const int mt = jj / 10;
  const int nt = xcd * 10 + (jj - mt * 10);
  const int m0 = mt * 32;
  if (m0 >= nact) return;                    // uniform early exit (handles nact=0)
  const int n0 = nt * 64;
  const int tid = threadIdx.x;               // 0..127

  __shared__ float As[2][32][32];   // [buf][k][m]
  __shared__ float Bs[2][32][64];   // [buf][k][n]

  // A staging: 32 rows x 32 k; thread = (row tid>>2, k-off (tid&3)*8), 2xfloat4
  const int ra = tid >> 2, qa = (tid & 3) * 8;
  int mr = m0 + ra; if (mr >= nact) mr = nact - 1;
  const int bbA = g_mlist[par][mr];
  const float* aptr = g_h + (size_t)(bbA*L_ + g_merged[bbA]) * 512 + qa;

  // B staging: 64 rows x 32 k; thread = (row tid>>1, k-off (tid&1)*16), 4xfloat4
  const int rb = tid >> 1, qb = (tid & 1) * 16;
  const int nr = n0 + rb;
  const float* bptr = (nr < NH5) ? Wc + (size_t)nr * 1024 + qb
                                 : Wc + (size_t)(nr - NH5) * 1024 + 512 + qb;

  const int tx = tid & 15, ty = tid >> 4;    // 16 n-groups x 8 m-groups

  float4 av0 = *(const float4*)(aptr),      av1 = *(const float4*)(aptr + 4);
  float4 bv0 = *(const float4*)(bptr),      bv1 = *(const float4*)(bptr + 4);
  float4 bv2 = *(const float4*)(bptr + 8),  bv3 = *(const float4*)(bptr + 12);
  As[0][qa+0][ra]=av0.x; As[0][qa+1][ra]=av0.y; As[0][qa+2][ra]=av0.z; As[0][qa+3][ra]=av0.w;
  As[0][qa+4][ra]=av1.x; As[0][qa+5][ra]=av1.y; As[0][qa+6][ra]=av1.z; As[0][qa+7][ra]=av1.w;
  Bs[0][qb+ 0][rb]=bv0.x; Bs[0][qb+ 1][rb]=bv0.y; Bs[0][qb+ 2][rb]=bv0.z; Bs[0][qb+ 3][rb]=bv0.w;
  Bs[0][qb+ 4][rb]=bv1.x; Bs[0][qb+ 5][rb]=bv1.y; Bs[0][qb+ 6][rb]=bv1.z; Bs[0][qb+ 7][rb]=bv1.w;
  Bs[0][qb+ 8][rb]=bv2.x; Bs[0][qb+ 9][rb]=bv2.y; Bs[0][qb+10][rb]=bv2.z; Bs[0][qb+11][rb]=bv2.w;
  Bs[0][qb+12][rb]=bv3.x; Bs[0][qb+13][rb]=bv3.y; Bs[0][qb+14][rb]=bv3.z; Bs[0][qb+15][rb]=bv3.w;
  __syncthreads();

  float acc[4][4] = {};
  for (int s = 0; s < 16; ++s) {
    const int cur = s & 1;
    if (s < 15) {                            // prefetch next K-step to regs
      const int ko = 32 * (s + 1);
      av0 = *(const float4*)(aptr + ko);      av1 = *(const float4*)(aptr + ko + 4);
      bv0 = *(const float4*)(bptr + ko);      bv1 = *(const float4*)(bptr + ko + 4);
      bv2 = *(const float4*)(bptr + ko + 8);  bv3 = *(const float4*)(bptr + ko + 12);
    }
#pragma unroll
    for (int k = 0; k < 32; k++) {
      float4 a4 = *(const float4*)&As[cur][k][ty*4];
      float4 b4 = *(const float4*)&Bs[cur][k][tx*4];
      const float af[4] = {a4.x, a4.y, a4.z, a4.w};
      const float bf[4] = {b4.x, b4.y, b4.z, b4.w};
#pragma unroll
      for (int i = 0; i < 4; i++)
#pragma unroll
        for (int j = 0; j < 4; j++)
          acc[i][j] = fmaf(af[i], bf[j], acc[i][j]);
    }
    if (s < 15) {                            // stage into the idle buffer
      const int nx = cur ^ 1;
      As[nx][qa+0][ra]=av0.x; As[nx][qa+1][ra]=av0.y; As[nx][qa+2][ra]=av0.z; As[nx][qa+3][ra]=av0.w;
      As[nx][qa+4][ra]=av1.x; As[nx][qa+5][ra]=av1.y; As[nx][qa+6][ra]=av1.z; As[nx][qa+7][ra]=av1.w;
      Bs[nx][qb+ 0][rb]=bv0.x; Bs[nx][qb+ 1][rb]=bv0.y; Bs[nx][qb+ 2][rb]=bv0.z; Bs[nx][qb+ 3][rb]=bv0.w;
      Bs[nx][qb+ 4][rb]=bv1.x; Bs[nx][qb+ 5][rb]=bv1.y; Bs[nx][qb+ 6][rb]=bv1.z; Bs[nx][qb+ 7][rb]=bv1.w;
      Bs[nx][qb+ 8][rb]=bv2.x; Bs[nx][qb+ 9][rb]=bv2.y; Bs[nx][qb+10][rb]=bv2.z; Bs[nx][qb+11][rb]=bv2.w;
      Bs[nx][qb+12][rb]=bv3.x; Bs[nx][qb+13][rb]=bv3.y; Bs[nx][qb+14][rb]=bv3.z; Bs[nx][qb+15][rb]=bv3.w;
      __syncthreads();                       // one barrier per K-step
    }
  }

#pragma unroll
  for (int i = 0; i < 4; i++) {
    int mrow = m0 + ty*4 + i;
    if (mrow >= nact) continue;
    int bb = g_mlist[par][mrow];
    size_t base = (size_t)(bb*L_ + g_merged[bb]) * NH5;
    int n = n0 + tx*4;                       // 4-chunks never straddle NH5 (2560%64==0)
    float4 v = make_float4(acc[i][0], acc[i][1], acc[i][2], acc[i][3]);
    if (n < NH5) *(float4*)(g_al + base + n)         = v;
    else         *(float4*)(g_ar + base + (n - NH5)) = v;
  }
}

// ---------------------------------------------------------------------------
extern "C" void kernel_launch(void* const* d_in, const int* in_sizes, int n_in,
                              void* d_out, int out_size, void* d_ws, size_t ws_size,
                              hipStream_t stream)
{
  (void)in_sizes; (void)n_in; (void)out_size; (void)d_ws; (void)ws_size;
  const float* x      = (const float*)d_in[0];
  const int*   length = (const int*)  d_in[1];
  const float* W_word = (const float*)d_in[2];
  const float* b_word = (const float*)d_in[3];
  const float* W_comp = (const float*)d_in[4];
  const float* b_comp = (const float*)d_in[5];
  const float* q      = (const float*)d_in[6];
  float* out = (float*)d_out;

  scan_init<<<1, 256, 0, stream>>>(length);

  // m-tiles of 256 cover NR <= 8192 (32 tiles, early-exit past NR)
  gemm_big<0><<<8*32,  256, 0, stream>>>(x, W_word, b_word);        // 8 nt x 32 mt
  gemm_big<1><<<40*32, 256, 0, stream>>>(nullptr, W_comp, nullptr); // 40 nt x 32 mt

  iter0_logits<<<dim3(L_-1, B_), 256, 0, stream>>>(length, b_comp, q);

  for (int i = 0; i < L_-1; i++) {
    select_merge<<<B_, 512, 0, stream>>>(i, length, b_comp, q, out);
    if (i < L_-2)
      gemm_iter<<<640, 128, 0, stream>>>(i & 1, W_comp);            // 8x10 nt x 8 mt
  }
}

// Round 12
// 1517.790 us; speedup vs baseline: 1.1399x; 1.1399x over previous
//
#include <hip/hip_runtime.h>
#include <cmath>

// (B, L, D, H) = (256, 32, 512, 512)
#define B_   256
#define L_   32
#define H_   512
#define NH5  2560   // 5*H
#define N2   5120   // 2*NH5 : [al | ar] output width
#define SCALE 0.044194173824159216f  // 1/sqrt(H)

// ---------------- persistent device state (re-initialized every launch) ----
__device__ float g_h [B_*L_*H_];          // [b][slot][j] node hidden
__device__ float g_c [B_*L_*H_];          // [b][slot][j] node cell
__device__ float g_al[(size_t)B_*L_*NH5]; // [b][slot][k] Wl @ h_slot
__device__ float g_ar[(size_t)B_*L_*NH5]; // [b][slot][k] Wr @ h_slot
__device__ float g_logit[B_*L_];          // pair logit keyed by LEFT slot
__device__ int   g_list[B_*L_];           // active slot list (sequence order)
__device__ int   g_count[B_];             // active node count
__device__ int   g_merged[B_];            // slot merged last iter (-1 done, -2 init)
__device__ int   g_mpos[B_];              // list position of last merge
__device__ int   g_rows[B_*L_];           // ordered compact list of active rows
__device__ int   g_nrows;
__device__ int   g_mlist[2][B_];          // batches merged this iter (parity)
__device__ int   g_cnt[2];

__device__ __forceinline__ float sigm(float x) { return 1.0f / (1.0f + expf(-x)); }

// vectorized gate loaders: d[u] = a[off+u] + b[off+u] + bc[off+u]
__device__ __forceinline__ void gate4(float* d, const float* __restrict__ a,
                                      const float* __restrict__ b,
                                      const float* __restrict__ bc, int off) {
  float4 x = *(const float4*)(a + off);
  float4 y = *(const float4*)(b + off);
  float4 z = *(const float4*)(bc + off);
  d[0]=x.x+y.x+z.x; d[1]=x.y+y.y+z.y; d[2]=x.z+y.z+z.z; d[3]=x.w+y.w+z.w;
}
__device__ __forceinline__ void gate2(float* d, const float* __restrict__ a,
                                      const float* __restrict__ b,
                                      const float* __restrict__ bc, int off) {
  float2 x = *(const float2*)(a + off);
  float2 y = *(const float2*)(b + off);
  float2 z = *(const float2*)(bc + off);
  d[0]=x.x+y.x+z.x; d[1]=x.y+y.y+z.y;
}

// ------ init: prefix-scan lengths, ordered row list, slot lists (fused) ----
__global__ __launch_bounds__(256) void scan_init(const int* __restrict__ length) {
  __shared__ int sw[4];
  __shared__ int s_off[256];
  __shared__ int s_len[256];
  const int t = threadIdx.x;
  const int len = length[t];
  s_len[t] = len;
  int v = len;
#pragma unroll
  for (int off = 1; off < 64; off <<= 1) {
    int o = __shfl_up(v, off, 64);
    if ((t & 63) >= off) v += o;
  }
  if ((t & 63) == 63) sw[t >> 6] = v;
  __syncthreads();
  int base = 0;
  for (int w = 0; w < (t >> 6); w++) base += sw[w];
  const int incl = base + v;
  s_off[t] = incl - len;
  if (t == 255) g_nrows = incl;
  g_count[t] = len; g_merged[t] = -2; g_mpos[t] = 0;
  if (t == 0) { g_cnt[0] = 0; g_cnt[1] = 0; }
  __syncthreads();
  for (int idx = t; idx < B_*L_; idx += 256) {      // fused fill_rows
    const int b = idx >> 5, s = idx & 31;
    g_list[idx] = s;
    if (s < s_len[b]) g_rows[s_off[b] + s] = idx;   // sorted by (b,slot)
  }
}

// ----- big row-compacted GEMMs: 256 thr, tile 256m x 128n, 16x8/thread -----
// EXACT r9/r10 body (measured best: 301-308us, VGPR 124, occ 17%, VALU ~61%).
// Session law (r1, r11): explicit LDS double-buffering ALWAYS loses here --
// it inflates VGPR past an occupancy step (56->124, 124->200) and costs more
// than the saved barrier. Single buffer, 2 syncs/K-step, register prefetch.
// Fragments: stride-64 grouping -> near-zero bank conflicts (1.4M measured).
// MODE 0: word GEMM  A=x rows   -> g_h|g_c (+b_word)   N=1024, 8 n-tiles
// MODE 1: leaf GEMM  A=g_h rows -> g_al|g_ar           N=5120, 40 n-tiles
template<int MODE>
__global__ __launch_bounds__(256) void gemm_big(
    const float* __restrict__ Aext,
    const float* __restrict__ Bm,
    const float* __restrict__ bias)
{
  const int NR = g_nrows;
  const int bid = blockIdx.x;
  const int xcd = bid & 7, jj = bid >> 3;
  const int ntp = (MODE == 0) ? 1 : 5;       // n-tiles per XCD
  const int mt = jj / ntp;
  const int nt = xcd * ntp + (jj - mt * ntp);
  const int m0 = mt * 256;
  if (m0 >= NR) return;                      // uniform early exit
  const int n0 = nt * 128;

  const int tid = threadIdx.x;
  const int w = tid >> 6, l = tid & 63;
  const int tx = (w & 1) * 8 + (l & 7);      // 0..15; cols tx*4 + 64q, q=0..1
  const int ty = (w >> 1) * 8 + (l >> 3);    // 0..15; rows ty*4 + 64p, p=0..3

  __shared__ float As[8][256];
  __shared__ float Bs[8][128];

  // A staging: 256 rows x 8 k; thread owns row tid (2 float4)
  int mr = m0 + tid; if (mr >= NR) mr = NR - 1;
  const float* Abase = (MODE == 0) ? Aext : g_h;
  const float* aptr = Abase + (size_t)g_rows[mr] * 512;

  // B staging: 128 rows x 8 k; thread = (row tid>>1, k-half (tid&1)*4)
  const int rb = tid >> 1, qb = (tid & 1) * 4;
  const float* bptr;
  {
    int nrow = n0 + rb;
    if (MODE == 0) bptr = Bm + (size_t)nrow * 512 + qb;
    else bptr = Bm + (nrow < NH5 ? (size_t)nrow * 1024
                                 : (size_t)(nrow - NH5) * 1024 + 512) + qb;
  }

  // register-prefetch pipeline: loads for k0+8 issue behind compute of k0
  float4 a0 = *(const float4*)(aptr), a1 = *(const float4*)(aptr + 4);
  float4 bv = *(const float4*)(bptr);
  float acc[16][8] = {};

  for (int k0 = 0; k0 < 512; k0 += 8) {
    __syncthreads();
    As[0][tid]=a0.x; As[1][tid]=a0.y; As[2][tid]=a0.z; As[3][tid]=a0.w;
    As[4][tid]=a1.x; As[5][tid]=a1.y; As[6][tid]=a1.z; As[7][tid]=a1.w;
    Bs[qb+0][rb]=bv.x; Bs[qb+1][rb]=bv.y; Bs[qb+2][rb]=bv.z; Bs[qb+3][rb]=bv.w;
    __syncthreads();
    if (k0 + 8 < 512) {
      a0 = *(const float4*)(aptr + k0 + 8);
      a1 = *(const float4*)(aptr + k0 + 12);
      bv = *(const float4*)(bptr + k0 + 8);
    }
#pragma unroll
    for (int k = 0; k < 8; k++) {
      float af[16], bf[8];
#pragma unroll
      for (int p = 0; p < 4; p++) {
        float4 t = *(const float4*)&As[k][ty*4 + 64*p];
        af[p*4+0]=t.x; af[p*4+1]=t.y; af[p*4+2]=t.z; af[p*4+3]=t.w;
      }
#pragma unroll
      for (int q = 0; q < 2; q++) {
        float4 t = *(const float4*)&Bs[k][tx*4 + 64*q];
        bf[q*4+0]=t.x; bf[q*4+1]=t.y; bf[q*4+2]=t.z; bf[q*4+3]=t.w;
      }
#pragma unroll
      for (int i = 0; i < 16; i++)
#pragma unroll
        for (int j = 0; j < 8; j++)
          acc[i][j] = fmaf(af[i], bf[j], acc[i][j]);
    }
  }

#pragma unroll
  for (int p = 0; p < 4; p++)
#pragma unroll
  for (int i = 0; i < 4; i++) {
    int mrow = m0 + 64*p + ty*4 + i;
    if (mrow >= NR) continue;
    int crow = g_rows[mrow];
#pragma unroll
    for (int q = 0; q < 2; q++) {
      int n = n0 + 64*q + tx*4;              // 4-aligned; never straddles 512/NH5
      float4 v = make_float4(acc[p*4+i][q*4+0], acc[p*4+i][q*4+1],
                             acc[p*4+i][q*4+2], acc[p*4+i][q*4+3]);
      if (MODE == 0) {
        float4 b4 = *(const float4*)(bias + n);
        v.x += b4.x; v.y += b4.y; v.z += b4.z; v.w += b4.w;
        if (n < H_) *(float4*)(g_h + (size_t)crow*H_ + n)        = v;
        else        *(float4*)(g_c + (size_t)crow*H_ + (n - H_)) = v;
      } else {
        if (n < NH5) *(float4*)(g_al + (size_t)crow*NH5 + n)         = v;
        else         *(float4*)(g_ar + (size_t)crow*NH5 + (n - NH5)) = v;
      }
    }
  }
}

// ---------------- iteration-0 logits (float2 vectorized) -------------------
__global__ __launch_bounds__(256) void iter0_logits(const int* __restrict__ length,
                                                    const float* __restrict__ bc,
                                                    const float* __restrict__ qv) {
  __shared__ float sred[4];
  const int p = blockIdx.x, b = blockIdx.y;
  if (p >= length[b] - 1) return;            // inactive pair: never read
  const float* al = g_al + (size_t)(b*L_ + p)*NH5;
  const float* ar = g_ar + (size_t)(b*L_ + p + 1)*NH5;
  const float* cl = g_c  + (size_t)(b*L_ + p)*H_;
  const float* cr = g_c  + (size_t)(b*L_ + p + 1)*H_;
  const int j0 = threadIdx.x * 2;
  float vi[2], vfl[2], vfr[2], vu[2], vo[2];
  gate2(vi , al, ar, bc,        j0);
  gate2(vfl, al, ar, bc, H_   + j0);
  gate2(vfr, al, ar, bc, 2*H_ + j0);
  gate2(vu , al, ar, bc, 3*H_ + j0);
  gate2(vo , al, ar, bc, 4*H_ + j0);
  float2 CL = *(const float2*)(cl + j0);
  float2 CR = *(const float2*)(cr + j0);
  float2 Q  = *(const float2*)(qv + j0);
  const float clv[2] = {CL.x, CL.y};
  const float crv[2] = {CR.x, CR.y};
  const float qq [2] = {Q.x, Q.y};
  float part = 0.f;
#pragma unroll
  for (int u = 0; u < 2; ++u) {
    float c = clv[u]*sigm(vfl[u]+1.f) + crv[u]*sigm(vfr[u]+1.f) + tanhf(vu[u])*sigm(vi[u]);
    float h = sigm(vo[u])*tanhf(c);
    part = fmaf(qq[u], h, part);
  }
#pragma unroll
  for (int off = 32; off; off >>= 1) part += __shfl_down(part, off, 64);
  if ((threadIdx.x & 63) == 0) sred[threadIdx.x >> 6] = part;
  __syncthreads();
  if (threadIdx.x == 0)
    g_logit[b*L_ + p] = (sred[0]+sred[1]+sred[2]+sred[3]) * SCALE;
}

// ---------------- per-iteration select + merge (+ final out write) ---------
// 512 threads (measured best): refresh keeps the EXACT 2x128-thread mapping
// (identical reduction order -> identical logits -> no argmax-flip risk);
// compose and output copy use all 512 threads, 1 element each.
// This round's ONE change vs r10: parallel list shift (was a serial tid==0
// loop of up to 30 dependent global RMWs with 511 lanes idle). Pure int
// permutation, read-all -> barrier -> write-all -> no numeric change.
__global__ __launch_bounds__(512) void select_merge(int iter,
    const int* __restrict__ length,
    const float* __restrict__ bc,
    const float* __restrict__ qv,
    float* __restrict__ out)
{
  __shared__ float sred[4];
  __shared__ int s_sel[3];
  const int b = blockIdx.x, tid = threadIdx.x;
  const bool fin = (iter == L_-2);
  if (b == 0 && tid == 0) g_cnt[(iter & 1) ^ 1] = 0;  // reset next iter's counter

  const int m     = g_count[b];
  const int pslot = g_merged[b];
  const int ppos  = g_mpos[b];
  int* list = g_list + b*L_;

  // ---- refresh the <=2 dirty pairs; threads 0..255 only, float4 over j ----
  if (iter > 0 && pslot >= 0) {
    const int half = tid >> 7, lt = tid & 127;
    int sl = -1, sr = -1;
    if (half == 0)      { if (ppos > 0)     { sl = list[ppos-1]; sr = list[ppos];   } }
    else if (half == 1) { if (ppos < m - 1) { sl = list[ppos];   sr = list[ppos+1]; } }
    float part = 0.f;
    if (sl >= 0) {
      const float* al = g_al + (size_t)(b*L_+sl)*NH5;
      const float* ar = g_ar + (size_t)(b*L_+sr)*NH5;
      const float* cl = g_c  + (size_t)(b*L_+sl)*H_;
      const float* cr = g_c  + (size_t)(b*L_+sr)*H_;
      const int j0 = lt * 4;
      float vi[4], vfl[4], vfr[4], vu[4], vo[4];
      gate4(vi , al, ar, bc,        j0);
      gate4(vfl, al, ar, bc, H_   + j0);
      gate4(vfr, al, ar, bc, 2*H_ + j0);
      gate4(vu , al, ar, bc, 3*H_ + j0);
      gate4(vo , al, ar, bc, 4*H_ + j0);
      float4 CL = *(const float4*)(cl + j0);
      float4 CR = *(const float4*)(cr + j0);
      float4 Q  = *(const float4*)(qv + j0);
      const float clv[4] = {CL.x,CL.y,CL.z,CL.w};
      const float crv[4] = {CR.x,CR.y,CR.z,CR.w};
      const float qq [4] = {Q.x,Q.y,Q.z,Q.w};
#pragma unroll
      for (int u = 0; u < 4; ++u) {
        float c = clv[u]*sigm(vfl[u]+1.f) + crv[u]*sigm(vfr[u]+1.f) + tanhf(vu[u])*sigm(vi[u]);
        float h = sigm(vo[u])*tanhf(c);
        part = fmaf(qq[u], h, part);
      }
    }
#pragma unroll
    for (int off = 32; off; off >>= 1) part += __shfl_down(part, off, 64);
    if ((tid & 63) == 0 && tid < 256) sred[tid >> 6] = part;
    __syncthreads();
    if (tid == 0   && ppos > 0)     g_logit[b*L_ + list[ppos-1]] = (sred[0]+sred[1])*SCALE;
    if (tid == 128 && ppos < m - 1) g_logit[b*L_ + list[ppos]]   = (sred[2]+sred[3])*SCALE;
  }

  const bool active = iter < (length[b] - 1);
  if (!active) {
    if (tid == 0) g_merged[b] = -1;
    if (fin)                                 // finished earlier: copy root
      out[(size_t)b*H_ + tid] = g_h[(size_t)(b*L_)*H_ + tid];
    return;
  }

  __syncthreads();   // refreshed g_logit visible block-wide

  // ---- wave-parallel argmax, first-max tie-break (lowest index) ----
  if (tid < 64) {
    float lg = -1e30f; int idx = tid;
    if (tid < m - 1) lg = g_logit[b*L_ + list[tid]];
#pragma unroll
    for (int off = 32; off; off >>= 1) {
      float olg = __shfl_down(lg, off, 64);
      int   oid = __shfl_down(idx, off, 64);
      if (olg > lg || (olg == lg && oid < idx)) { lg = olg; idx = oid; }
    }
    if (tid == 0) { s_sel[0] = idx; s_sel[1] = list[idx]; s_sel[2] = list[idx+1]; }
  }
  __syncthreads();
  const int pos = s_sel[0], sl = s_sel[1], sr = s_sel[2];

  // ---- merge compose (store h,c; 1 element/thread, 512 threads) ----
  {
    const float* al = g_al + (size_t)(b*L_+sl)*NH5;
    const float* ar = g_ar + (size_t)(b*L_+sr)*NH5;
    float*       cl = g_c  + (size_t)(b*L_+sl)*H_;
    const float* cr = g_c  + (size_t)(b*L_+sr)*H_;
    float*       hl = g_h  + (size_t)(b*L_+sl)*H_;
    const int j = tid;                       // H_ == 512 == blockDim
    float vi  = al[j]       + ar[j]       + bc[j];
    float vfl = al[H_+j]    + ar[H_+j]    + bc[H_+j];
    float vfr = al[2*H_+j]  + ar[2*H_+j]  + bc[2*H_+j];
    float vu  = al[3*H_+j]  + ar[3*H_+j]  + bc[3*H_+j];
    float vo  = al[4*H_+j]  + ar[4*H_+j]  + bc[4*H_+j];
    float c = cl[j]*sigm(vfl+1.f) + cr[j]*sigm(vfr+1.f) + tanhf(vu)*sigm(vi);
    float h = sigm(vo)*tanhf(c);
    cl[j] = c; hl[j] = h;                    // same-thread j: no RAW hazard
    if (fin)                                 // final merge: sl==0==root
      out[(size_t)b*H_ + j] = h;
  }

  // ---- parallel list shift: read-all -> barrier -> write-all ----
  {
    const bool doshift = (tid >= pos + 1) && (tid <= m - 2);
    int lv = 0;
    if (doshift) lv = list[tid + 1];
    __syncthreads();
    if (doshift) list[tid] = lv;
  }
  if (tid == 0) {
    g_count[b]  = m - 1;
    g_merged[b] = sl;
    g_mpos[b]   = pos;
    int k = atomicAdd(&g_cnt[iter & 1], 1);
    g_mlist[iter & 1][k] = b;
  }
}

// ------ per-iteration a_l/a_r GEMM: 32x64 tile, 4x4/thread, 128 threads ----
// EXACT r10 body (measured best loop: 1540 total). Grid 640, XCD swizzle.
__global__ __launch_bounds__(128) void gemm_iter(int par, const float* __restrict__ Wc)
{
  const int nact = g_cnt[par];
  const int bid = blockIdx.x;                // 640 blocks = 8 xcd x 10 nt x 8 mt
  const int xcd = bid & 7, jj = bid >> 3;    // jj 0..79
  const int mt = jj / 10;
  const int nt = xcd * 10 + (jj - mt * 10);
  const int m0 = mt * 32;
  if (m0 >= nact) return;                    // uniform early exit (handles nact=0)
  const int n0 = nt * 64;
  const int tid = threadIdx.x;               // 0..127

  __shared__ float As[2][32][32];   // [buf][k][m]
  __shared__ float Bs[2][32][64];   // [buf][k][n]

  // A staging: 32 rows x 32 k; thread = (row tid>>2, k-off (tid&3)*8), 2xfloat4
  const int ra = tid >> 2, qa = (tid & 3) * 8;
  int mr = m0 + ra; if (mr >= nact) mr = nact - 1;
  const int bbA = g_mlist[par][mr];
  const float* aptr = g_h + (size_t)(bbA*L_ + g_merged[bbA]) * 512 + qa;

  // B staging: 64 rows x 32 k; thread = (row tid>>1, k-off (tid&1)*16), 4xfloat4
  const int rb = tid >> 1, qb = (tid & 1) * 16;
  const int nr = n0 + rb;
  const float* bptr = (nr < NH5) ? Wc + (size_t)nr * 1024 + qb
                                 : Wc + (size_t)(nr - NH5) * 1024 + 512 + qb;

  const int tx = tid & 15, ty = tid >> 4;    // 16 n-groups x 8 m-groups

  float4 av0 = *(const float4*)(aptr),      av1 = *(const float4*)(aptr + 4);
  float4 bv0 = *(const float4*)(bptr),      bv1 = *(const float4*)(bptr + 4);
  float4 bv2 = *(const float4*)(bptr + 8),  bv3 = *(const float4*)(bptr + 12);
  As[0][qa+0][ra]=av0.x; As[0][qa+1][ra]=av0.y; As[0][qa+2][ra]=av0.z; As[0][qa+3][ra]=av0.w;
  As[0][qa+4][ra]=av1.x; As[0][qa+5][ra]=av1.y; As[0][qa+6][ra]=av1.z; As[0][qa+7][ra]=av1.w;
  Bs[0][qb+ 0][rb]=bv0.x; Bs[0][qb+ 1][rb]=bv0.y; Bs[0][qb+ 2][rb]=bv0.z; Bs[0][qb+ 3][rb]=bv0.w;
  Bs[0][qb+ 4][rb]=bv1.x; Bs[0][qb+ 5][rb]=bv1.y; Bs[0][qb+ 6][rb]=bv1.z; Bs[0][qb+ 7][rb]=bv1.w;
  Bs[0][qb+ 8][rb]=bv2.x; Bs[0][qb+ 9][rb]=bv2.y; Bs[0][qb+10][rb]=bv2.z; Bs[0][qb+11][rb]=bv2.w;
  Bs[0][qb+12][rb]=bv3.x; Bs[0][qb+13][rb]=bv3.y; Bs[0][qb+14][rb]=bv3.z; Bs[0][qb+15][rb]=bv3.w;
  __syncthreads();

  float acc[4][4] = {};
  for (int s = 0; s < 16; ++s) {
    const int cur = s & 1;
    if (s < 15) {                            // prefetch next K-step to regs
      const int ko = 32 * (s + 1);
      av0 = *(const float4*)(aptr + ko);      av1 = *(const float4*)(aptr + ko + 4);
      bv0 = *(const float4*)(bptr + ko);      bv1 = *(const float4*)(bptr + ko + 4);
      bv2 = *(const float4*)(bptr + ko + 8);  bv3 = *(const float4*)(bptr + ko + 12);
    }
#pragma unroll
    for (int k = 0; k < 32; k++) {
      float4 a4 = *(const float4*)&As[cur][k][ty*4];
      float4 b4 = *(const float4*)&Bs[cur][k][tx*4];
      const float af[4] = {a4.x, a4.y, a4.z, a4.w};
      const float bf[4] = {b4.x, b4.y, b4.z, b4.w};
#pragma unroll
      for (int i = 0; i < 4; i++)
#pragma unroll
        for (int j = 0; j < 4; j++)
          acc[i][j] = fmaf(af[i], bf[j], acc[i][j]);
    }
    if (s < 15) {                            // stage into the idle buffer
      const int nx = cur ^ 1;
      As[nx][qa+0][ra]=av0.x; As[nx][qa+1][ra]=av0.y; As[nx][qa+2][ra]=av0.z; As[nx][qa+3][ra]=av0.w;
      As[nx][qa+4][ra]=av1.x; As[nx][qa+5][ra]=av1.y; As[nx][qa+6][ra]=av1.z; As[nx][qa+7][ra]=av1.w;
      Bs[nx][qb+ 0][rb]=bv0.x; Bs[nx][qb+ 1][rb]=bv0.y; Bs[nx][qb+ 2][rb]=bv0.z; Bs[nx][qb+ 3][rb]=bv0.w;
      Bs[nx][qb+ 4][rb]=bv1.x; Bs[nx][qb+ 5][rb]=bv1.y; Bs[nx][qb+ 6][rb]=bv1.z; Bs[nx][qb+ 7][rb]=bv1.w;
      Bs[nx][qb+ 8][rb]=bv2.x; Bs[nx][qb+ 9][rb]=bv2.y; Bs[nx][qb+10][rb]=bv2.z; Bs[nx][qb+11][rb]=bv2.w;
      Bs[nx][qb+12][rb]=bv3.x; Bs[nx][qb+13][rb]=bv3.y; Bs[nx][qb+14][rb]=bv3.z; Bs[nx][qb+15][rb]=bv3.w;
      __syncthreads();                       // one barrier per K-step
    }
  }

#pragma unroll
  for (int i = 0; i < 4; i++) {
    int mrow = m0 + ty*4 + i;
    if (mrow >= nact) continue;
    int bb = g_mlist[par][mrow];
    size_t base = (size_t)(bb*L_ + g_merged[bb]) * NH5;
    int n = n0 + tx*4;                       // 4-chunks never straddle NH5 (2560%64==0)
    float4 v = make_float4(acc[i][0], acc[i][1], acc[i][2], acc[i][3]);
    if (n < NH5) *(float4*)(g_al + base + n)         = v;
    else         *(float4*)(g_ar + base + (n - NH5)) = v;
  }
}

// ---------------------------------------------------------------------------
extern "C" void kernel_launch(void* const* d_in, const int* in_sizes, int n_in,
                              void* d_out, int out_size, void* d_ws, size_t ws_size,
                              hipStream_t stream)
{
  (void)in_sizes; (void)n_in; (void)out_size; (void)d_ws; (void)ws_size;
  const float* x      = (const float*)d_in[0];
  const int*   length = (const int*)  d_in[1];
  const float* W_word = (const float*)d_in[2];
  const float* b_word = (const float*)d_in[3];
  const float* W_comp = (const float*)d_in[4];
  const float* b_comp = (const float*)d_in[5];
  const float* q      = (const float*)d_in[6];
  float* out = (float*)d_out;

  scan_init<<<1, 256, 0, stream>>>(length);

  // m-tiles of 256 cover NR <= 8192 (32 tiles, early-exit past NR)
  gemm_big<0><<<8*32,  256, 0, stream>>>(x, W_word, b_word);        // 8 nt x 32 mt
  gemm_big<1><<<40*32, 256, 0, stream>>>(nullptr, W_comp, nullptr); // 40 nt x 32 mt

  iter0_logits<<<dim3(L_-1, B_), 256, 0, stream>>>(length, b_comp, q);

  for (int i = 0; i < L_-1; i++) {
    select_merge<<<B_, 512, 0, stream>>>(i, length, b_comp, q, out);
    if (i < L_-2)
      gemm_iter<<<640, 128, 0, stream>>>(i & 1, W_comp);            // 8x10 nt x 8 mt
  }
}